// Round 9
// baseline (621.539 us; speedup 1.0000x reference)
//
#include <hip/hip_runtime.h>

// ---------------- problem constants ----------------
#define DIM    192
#define HEADS  6
#define HD     32
#define NTOK   64
#define NWIN   512
#define NBLK   2048
#define NTASK  (NBLK*HEADS)   // 12288 (window,head) tasks
#define WMAT   (DIM*DIM)      // 36864 elements per weight matrix
#define TPITCH 36             // private LDS transpose tile pitch (ushorts)

typedef short  bf16x4 __attribute__((ext_vector_type(4)));
typedef short  bf16x8 __attribute__((ext_vector_type(8)));
typedef float  f32x4  __attribute__((ext_vector_type(4)));

// NOTE: guard must be device-pass only — on the HOST pass of HIP's dual
// compilation __has_builtin(amdgcn builtins) is false and #error fires.
#if defined(__HIP_DEVICE_COMPILE__)
#if !__has_builtin(__builtin_amdgcn_mfma_f32_16x16x32_bf16)
#error "missing __builtin_amdgcn_mfma_f32_16x16x32_bf16"
#endif
#if !__has_builtin(__builtin_amdgcn_mfma_f32_16x16x16bf16_1k)
#error "missing __builtin_amdgcn_mfma_f32_16x16x16bf16_1k"
#endif
#endif

static __device__ __forceinline__ unsigned short f2bf(float f){
  unsigned u = __builtin_bit_cast(unsigned, f);
  u += 0x7FFFu + ((u >> 16) & 1u);          // round-to-nearest-even
  return (unsigned short)(u >> 16);
}

static __device__ __forceinline__ f32x4 mfma32(bf16x8 a, bf16x8 b, f32x4 c){
  return __builtin_amdgcn_mfma_f32_16x16x32_bf16(a, b, c, 0, 0, 0);
}
static __device__ __forceinline__ f32x4 mfma16(bf16x4 a, bf16x4 b, f32x4 c){
  return __builtin_amdgcn_mfma_f32_16x16x16bf16_1k(a, b, c, 0, 0, 0);
}

// bf16 weight fragment: ONE 16B load (weights pre-converted in d_ws).
static __device__ __forceinline__ bf16x8 wfrag(const unsigned short* __restrict__ W, int row, int k0){
  return *(const bf16x8*)(W + row*DIM + k0);
}

// fp32 x fragment straight from global (same-window waves share L1/L2).
static __device__ __forceinline__ bf16x8 xfrag(const float* __restrict__ X, int row, int k0){
  const float4 a = *(const float4*)(X + row*DIM + k0);
  const float4 b = *(const float4*)(X + row*DIM + k0 + 4);
  bf16x8 r;
  r[0]=(short)f2bf(a.x); r[1]=(short)f2bf(a.y); r[2]=(short)f2bf(a.z); r[3]=(short)f2bf(a.w);
  r[4]=(short)f2bf(b.x); r[5]=(short)f2bf(b.y); r[6]=(short)f2bf(b.z); r[7]=(short)f2bf(b.w);
  return r;
}

// ---- attn_mask dtype probe: 0 = int32 {0,1}, 1 = packed bytes, 2 = float32 ----
__global__ void detect_amask_kernel(const unsigned int* __restrict__ am, int* __restrict__ mode){
  __shared__ int sawFloat, sawByte;
  if (threadIdx.x == 0){ sawFloat = 0; sawByte = 0; }
  __syncthreads();
  const uint4 ld = ((const uint4*)am)[threadIdx.x];   // 256 threads * 16B = 4KB
  unsigned w[4] = {ld.x, ld.y, ld.z, ld.w};
  int f = 0, bm = 0;
  #pragma unroll
  for (int i = 0; i < 4; ++i){
    if (w[i] == 0x3F800000u) f = 1;
    else if (w[i] & ~1u)     bm = 1;
  }
  if (f)  atomicOr(&sawFloat, 1);
  if (bm) atomicOr(&sawByte, 1);
  __syncthreads();
  if (threadIdx.x == 0) *mode = sawFloat ? 2 : (sawByte ? 1 : 0);
}

// bias_t[h][n][m] = rpb_table[rel_idx[n][m]*HEADS + h]  (float4-loadable over m)
__global__ void bias_pre_kernel(const float* __restrict__ rpb, const int* __restrict__ rel_idx,
                                float* __restrict__ bias_t){
  const int e = blockIdx.x*256 + threadIdx.x;
  if (e >= HEADS*NTOK*NTOK) return;
  const int n = (e >> 6) & 63, m = e & 63;
  bias_t[e] = rpb[rel_idx[n*NTOK + m]*HEADS + (e >> 12)];
}

// convert the 4 weight matrices fp32 -> bf16 once (Wq,Wk,Wv,Wp contiguous in ws)
__global__ void wconv_kernel(const float* __restrict__ Wq, const float* __restrict__ Wk,
                             const float* __restrict__ Wv, const float* __restrict__ Wp,
                             unsigned short* __restrict__ wbf){
  const int e4 = blockIdx.x*256 + threadIdx.x;       // 4*36864/4 = 36864 float4s
  if (e4 >= 4*WMAT/4) return;
  const int mat = e4 / (WMAT/4);
  const int off = e4 - mat*(WMAT/4);
  const float* src = (mat==0)?Wq:(mat==1)?Wk:(mat==2)?Wv:Wp;
  const float4 f = ((const float4*)src)[off];
  unsigned short* dst = wbf + mat*WMAT + off*4;
  dst[0]=f2bf(f.x); dst[1]=f2bf(f.y); dst[2]=f2bf(f.z); dst[3]=f2bf(f.w);
}

// Fragment layout facts used (gfx950, m89-verified family):
//   mfma 16x16x32: A[row=l&15][k=8g+i], B[k=8g+i][col=l&15], C: col=l&15,row=4g+r
//   mfma 16x16x16: A[row=l&15][k=4g+r], B[k=4g+r][col=l&15], C: col=l&15,row=4g+r
// Block = 256 threads = 4 waves; each wave = one independent (window,head)
// task (task = w*6+h so co-blocked waves share the window's x in L1).
// ZERO barriers. Attention output leaves through a per-wave private LDS
// transpose tile (same-wave ds ordering, no sync) and is stored as clean
// 64B segments into the unused tail half of the fp32 out rows.
__global__ __launch_bounds__(256, 4) void attn_kernel(
  const float* __restrict__ q, const float* __restrict__ kin, const float* __restrict__ vin,
  const float* __restrict__ mask, const void* __restrict__ amask,
  const unsigned short* __restrict__ wbf,
  const float* __restrict__ bq, const float* __restrict__ bk, const float* __restrict__ bv,
  const float* __restrict__ bias_t, const int* __restrict__ mflag,
  float* __restrict__ outf)
{
  __shared__ unsigned short xt[4][NTOK * TPITCH];   // 4 x 4.6 KB private tiles

  const int t    = threadIdx.x;
  const int wv   = t >> 6;
  const int task = blockIdx.x*4 + wv;               // < 12288
  const int b    = task / HEADS;
  const int h    = task - b*HEADS;
  const int lane = t & 63;
  const int l15  = lane & 15;
  const int g    = lane >> 4;
  const int c0   = h * HD;
  const size_t base = (size_t)b * (NTOK * DIM);
  const float scale = 0.17677669529663687f;   // 1/sqrt(32)
  const f32x4 fz = {0.f, 0.f, 0.f, 0.f};

  const unsigned short* Wq = wbf;
  const unsigned short* Wk = wbf + WMAT;
  const unsigned short* Wv = wbf + 2*WMAT;
  const float* qb = q   + base;
  const float* kb = kin + base;
  const float* vb = vin + base;

  bf16x4 Qf[4][2], Kf[4][2], Vf[2][4];

  {  // Q projection (transposed): Qh^T[c][n]
    f32x4 acc[2][4];
    #pragma unroll
    for (int a0=0;a0<2;++a0){
      #pragma unroll
      for (int a1=0;a1<4;++a1) acc[a0][a1] = fz;
    }
    #pragma unroll
    for (int kt = 0; kt < 6; ++kt){
      const int k0 = kt*32 + g*8;
      const bf16x8 w0 = wfrag(Wq, c0 + l15, k0);
      const bf16x8 w1 = wfrag(Wq, c0 + 16 + l15, k0);
      #pragma unroll
      for (int nt = 0; nt < 4; ++nt){
        const bf16x8 xf = xfrag(qb, nt*16 + l15, k0);
        acc[0][nt] = mfma32(w0, xf, acc[0][nt]);
        acc[1][nt] = mfma32(w1, xf, acc[1][nt]);
      }
    }
    #pragma unroll
    for (int dt = 0; dt < 2; ++dt){
      const float4 bb = *(const float4*)(bq + c0 + dt*16 + g*4);
      #pragma unroll
      for (int nt = 0; nt < 4; ++nt){
        bf16x4 f;
        f[0]=(short)f2bf((acc[dt][nt][0]+bb.x)*scale);
        f[1]=(short)f2bf((acc[dt][nt][1]+bb.y)*scale);
        f[2]=(short)f2bf((acc[dt][nt][2]+bb.z)*scale);
        f[3]=(short)f2bf((acc[dt][nt][3]+bb.w)*scale);
        Qf[nt][dt] = f;
      }
    }
  }
  {  // K projection (transposed): Kh^T[c][m]
    f32x4 acc[2][4];
    #pragma unroll
    for (int a0=0;a0<2;++a0){
      #pragma unroll
      for (int a1=0;a1<4;++a1) acc[a0][a1] = fz;
    }
    #pragma unroll
    for (int kt = 0; kt < 6; ++kt){
      const int k0 = kt*32 + g*8;
      const bf16x8 w0 = wfrag(Wk, c0 + l15, k0);
      const bf16x8 w1 = wfrag(Wk, c0 + 16 + l15, k0);
      #pragma unroll
      for (int mt = 0; mt < 4; ++mt){
        const bf16x8 xf = xfrag(kb, mt*16 + l15, k0);
        acc[0][mt] = mfma32(w0, xf, acc[0][mt]);
        acc[1][mt] = mfma32(w1, xf, acc[1][mt]);
      }
    }
    #pragma unroll
    for (int dt = 0; dt < 2; ++dt){
      const float4 bb = *(const float4*)(bk + c0 + dt*16 + g*4);
      #pragma unroll
      for (int mt = 0; mt < 4; ++mt){
        bf16x4 f;
        f[0]=(short)f2bf(acc[dt][mt][0]+bb.x);
        f[1]=(short)f2bf(acc[dt][mt][1]+bb.y);
        f[2]=(short)f2bf(acc[dt][mt][2]+bb.z);
        f[3]=(short)f2bf(acc[dt][mt][3]+bb.w);
        Kf[mt][dt] = f;
      }
    }
  }
  {  // V projection (normal): Vh[m][c] -> C regs ARE Vh^T A-frags
    f32x4 acc[4][2];
    #pragma unroll
    for (int a0=0;a0<4;++a0){
      #pragma unroll
      for (int a1=0;a1<2;++a1) acc[a0][a1] = fz;
    }
    #pragma unroll
    for (int kt = 0; kt < 6; ++kt){
      const int k0 = kt*32 + g*8;
      const bf16x8 w0 = wfrag(Wv, c0 + l15, k0);
      const bf16x8 w1 = wfrag(Wv, c0 + 16 + l15, k0);
      #pragma unroll
      for (int mt = 0; mt < 4; ++mt){
        const bf16x8 xf = xfrag(vb, mt*16 + l15, k0);
        acc[mt][0] = mfma32(xf, w0, acc[mt][0]);
        acc[mt][1] = mfma32(xf, w1, acc[mt][1]);
      }
    }
    const float bv0 = bv[c0 + l15];
    const float bv1 = bv[c0 + 16 + l15];
    #pragma unroll
    for (int mt = 0; mt < 4; ++mt){
      bf16x4 f0, f1;
      f0[0]=(short)f2bf(acc[mt][0][0]+bv0); f0[1]=(short)f2bf(acc[mt][0][1]+bv0);
      f0[2]=(short)f2bf(acc[mt][0][2]+bv0); f0[3]=(short)f2bf(acc[mt][0][3]+bv0);
      f1[0]=(short)f2bf(acc[mt][1][0]+bv1); f1[1]=(short)f2bf(acc[mt][1][1]+bv1);
      f1[2]=(short)f2bf(acc[mt][1][2]+bv1); f1[3]=(short)f2bf(acc[mt][1][3]+bv1);
      Vf[0][mt] = f0;  // A[row=d=l15][k=m=4g+r]
      Vf[1][mt] = f1;
    }
  }

  // ---------- S^T = Kh * Qh^T : C[col=n=l15+16nt][row=m=4g+r+16mt] ----------
  f32x4 s[4][4];
  #pragma unroll
  for (int mt = 0; mt < 4; ++mt){
    #pragma unroll
    for (int nt = 0; nt < 4; ++nt){
      f32x4 a = mfma16(Kf[mt][0], Qf[nt][0], fz);
      s[mt][nt] = mfma16(Kf[mt][1], Qf[nt][1], a);
    }
  }

  // ---------- mask + attn_mask + bias folded per-lane from global ----------
  {
    const int mode = mflag[0];
    const float* mrow = mask + (size_t)(b & (NWIN-1)) * (NTOK*NTOK);
    const float* brow = bias_t + h * (NTOK*NTOK);
    #pragma unroll
    for (int nt = 0; nt < 4; ++nt){
      const int n = nt*16 + l15;
      #pragma unroll
      for (int mt = 0; mt < 4; ++mt){
        const int off = n*NTOK + mt*16 + g*4;
        const float4 mk = *(const float4*)(mrow + off);
        const float4 bi = *(const float4*)(brow + off);
        float am[4];
        if (mode == 0){
          const int4 a4 = *(const int4*)((const int*)amask + (size_t)b*(NTOK*NTOK) + off);
          am[0] = a4.x ? -1e9f : 0.f; am[1] = a4.y ? -1e9f : 0.f;
          am[2] = a4.z ? -1e9f : 0.f; am[3] = a4.w ? -1e9f : 0.f;
        } else if (mode == 1){
          const unsigned a4 = *(const unsigned*)((const unsigned char*)amask + (size_t)b*(NTOK*NTOK) + off);
          am[0] = (a4 & 0x000000FFu) ? -1e9f : 0.f; am[1] = (a4 & 0x0000FF00u) ? -1e9f : 0.f;
          am[2] = (a4 & 0x00FF0000u) ? -1e9f : 0.f; am[3] = (a4 & 0xFF000000u) ? -1e9f : 0.f;
        } else {
          const float4 a4 = *(const float4*)((const float*)amask + (size_t)b*(NTOK*NTOK) + off);
          am[0] = (a4.x != 0.f) ? -1e9f : 0.f; am[1] = (a4.y != 0.f) ? -1e9f : 0.f;
          am[2] = (a4.z != 0.f) ? -1e9f : 0.f; am[3] = (a4.w != 0.f) ? -1e9f : 0.f;
        }
        s[mt][nt][0] += mk.x + bi.x + am[0];
        s[mt][nt][1] += mk.y + bi.y + am[1];
        s[mt][nt][2] += mk.z + bi.z + am[2];
        s[mt][nt][3] += mk.w + bi.w + am[3];
      }
    }
  }

  // ---------- softmax over m (in-lane 16 + shfl_xor 16,32) ----------
  bf16x4 Pf[4][4];
  #pragma unroll
  for (int nt = 0; nt < 4; ++nt){
    float mx = -3.0e38f;
    #pragma unroll
    for (int mt = 0; mt < 4; ++mt){
      #pragma unroll
      for (int r = 0; r < 4; ++r) mx = fmaxf(mx, s[mt][nt][r]);
    }
    mx = fmaxf(mx, __shfl_xor(mx, 16, 64));
    mx = fmaxf(mx, __shfl_xor(mx, 32, 64));
    float sum = 0.f;
    #pragma unroll
    for (int mt = 0; mt < 4; ++mt){
      #pragma unroll
      for (int r = 0; r < 4; ++r){
        const float e = __expf(s[mt][nt][r] - mx);
        s[mt][nt][r] = e;
        sum += e;
      }
    }
    sum += __shfl_xor(sum, 16, 64);
    sum += __shfl_xor(sum, 32, 64);
    const float inv = 1.0f / sum;
    #pragma unroll
    for (int ms = 0; ms < 4; ++ms){
      bf16x4 f;
      f[0]=(short)f2bf(s[ms][nt][0]*inv); f[1]=(short)f2bf(s[ms][nt][1]*inv);
      f[2]=(short)f2bf(s[ms][nt][2]*inv); f[3]=(short)f2bf(s[ms][nt][3]*inv);
      Pf[nt][ms] = f;   // B-frag: P^T[m=4g+r+16ms][n=l15+16nt]
    }
  }

  // ---------- out^T = Vh^T * P^T : C[col=n][row=d=4g+r+16dt] ----------
  f32x4 o[2][4];
  #pragma unroll
  for (int a0=0;a0<2;++a0){
    #pragma unroll
    for (int a1=0;a1<4;++a1) o[a0][a1] = fz;
  }
  #pragma unroll
  for (int ms = 0; ms < 4; ++ms){
    #pragma unroll
    for (int dt = 0; dt < 2; ++dt){
      #pragma unroll
      for (int nt = 0; nt < 4; ++nt){
        o[dt][nt] = mfma16(Vf[dt][ms], Pf[nt][ms], o[dt][nt]);
      }
    }
  }

  // ---------- private LDS transpose (same-wave, no barrier needed) ----------
  unsigned short* myt = &xt[wv][0];
  #pragma unroll
  for (int dt = 0; dt < 2; ++dt){
    #pragma unroll
    for (int nt = 0; nt < 4; ++nt){
      const int n   = nt*16 + l15;
      const int col = dt*16 + g*4;        // head-local column
      uint2 u;
      u.x = (unsigned)f2bf(o[dt][nt][0]) | ((unsigned)f2bf(o[dt][nt][1]) << 16);
      u.y = (unsigned)f2bf(o[dt][nt][2]) | ((unsigned)f2bf(o[dt][nt][3]) << 16);
      *(uint2*)(myt + n*TPITCH + col) = u;
    }
  }

  // ---------- coalesced 64B-segment stores into out row tails ----------
  // out row n: bytes [0,768) fp32; bf16 stash row at [384,768); head h owns
  // bytes [384+64h, 384+64h+64) of each row -> disjoint across waves.
  {
    char* tail = (char*)outf + (size_t)b*NTOK*768 + 384 + (size_t)c0*2;
    const int nloc = lane >> 4;           // 4 rows per iteration
    const int dwi  = lane & 15;           // dword within 64B run
    #pragma unroll
    for (int it = 0; it < 16; ++it){
      const int n = it*4 + nloc;
      const unsigned d = *(const unsigned*)(myt + n*TPITCH + dwi*2);
      *(unsigned*)(tail + (size_t)n*768 + dwi*4) = d;
    }
  }
}

// out[n][c'] = xout[n][:] @ Wp[c'][:]^T + bp ; xout bf16 read from out-row tails,
// fp32 result overwrites the full row. Store values depend (via MFMA chain) on
// all of the wave's tail loads, and each wave only touches its own 16 rows.
__global__ __launch_bounds__(256, 4) void oproj_kernel(
  float* __restrict__ outf, const unsigned short* __restrict__ wbf,
  const float* __restrict__ bp)
{
  const int t    = threadIdx.x;
  const int wv   = t >> 6;
  const int lane = t & 63;
  const int l15  = lane & 15;
  const int g    = lane >> 4;
  const int n0   = (blockIdx.x*4 + wv) * 16;     // 16 tokens per wave
  const unsigned short* Wp = wbf + 3*WMAT;
  const f32x4 fz = {0.f, 0.f, 0.f, 0.f};

  f32x4 acc[12];
  #pragma unroll
  for (int ct = 0; ct < 12; ++ct) acc[ct] = fz;

  #pragma unroll
  for (int kt = 0; kt < 6; ++kt){
    const int k0 = kt*32 + g*8;
    const bf16x8 a = *(const bf16x8*)((const char*)outf + (size_t)(n0 + l15)*768 + 384 + k0*2);
    #pragma unroll
    for (int ct = 0; ct < 12; ++ct){
      const bf16x8 w = wfrag(Wp, ct*16 + l15, k0);
      acc[ct] = mfma32(a, w, acc[ct]);
    }
  }
  #pragma unroll
  for (int ct = 0; ct < 12; ++ct){
    const float badd = bp[ct*16 + l15];
    #pragma unroll
    for (int r = 0; r < 4; ++r){
      outf[(size_t)(n0 + g*4 + r)*DIM + ct*16 + l15] = acc[ct][r] + badd;
    }
  }
}

extern "C" void kernel_launch(void* const* d_in, const int* in_sizes, int n_in,
                              void* d_out, int out_size, void* d_ws, size_t ws_size,
                              hipStream_t stream){
  const float* q     = (const float*)d_in[0];
  const float* k     = (const float*)d_in[1];
  const float* v     = (const float*)d_in[2];
  const float* mask  = (const float*)d_in[3];
  const void*  amask = d_in[4];               // dtype resolved by device probe
  const float* Wq    = (const float*)d_in[5];
  const float* bq    = (const float*)d_in[6];
  const float* Wk    = (const float*)d_in[7];
  const float* bk    = (const float*)d_in[8];
  const float* Wv    = (const float*)d_in[9];
  const float* bv    = (const float*)d_in[10];
  const float* Wp    = (const float*)d_in[11];
  const float* bp    = (const float*)d_in[12];
  const float* rpb   = (const float*)d_in[13];
  const int*   ridx  = (const int*)d_in[14];
  float* out = (float*)d_out;

  // workspace layout: [0,98304) bias_t | [98304,98308) mflag | [98560, +294912) wbf
  float*          bias_t = (float*)d_ws;
  int*            mflag  = (int*)((char*)d_ws + 98304);
  unsigned short* wbf    = (unsigned short*)((char*)d_ws + 98560);

  detect_amask_kernel<<<1, 256, 0, stream>>>((const unsigned int*)amask, mflag);
  bias_pre_kernel<<<96, 256, 0, stream>>>(rpb, ridx, bias_t);
  wconv_kernel<<<144, 256, 0, stream>>>(Wq, Wk, Wv, Wp, wbf);
  attn_kernel<<<NTASK/4, 256, 0, stream>>>(q, k, v, mask, amask, wbf,
                                           bq, bk, bv, bias_t, mflag, out);
  oproj_kernel<<<NBLK, 256, 0, stream>>>(out, wbf, bp);
}

// Round 10
// 407.909 us; speedup vs baseline: 1.5237x; 1.5237x over previous
//
#include <hip/hip_runtime.h>

// ---------------- problem constants ----------------
#define DIM    192
#define HEADS  6
#define HD     32
#define NTOK   64
#define NWIN   512
#define NBLK   2048
#define WMAT   (DIM*DIM)      // 36864 elements per weight matrix
#define XPITCH 200            // LDS x-tile row pitch (ushorts)

typedef short  bf16x4 __attribute__((ext_vector_type(4)));
typedef short  bf16x8 __attribute__((ext_vector_type(8)));
typedef float  f32x4  __attribute__((ext_vector_type(4)));

#if defined(__HIP_DEVICE_COMPILE__)
#if !__has_builtin(__builtin_amdgcn_mfma_f32_16x16x32_bf16)
#error "missing __builtin_amdgcn_mfma_f32_16x16x32_bf16"
#endif
#if !__has_builtin(__builtin_amdgcn_mfma_f32_16x16x16bf16_1k)
#error "missing __builtin_amdgcn_mfma_f32_16x16x16bf16_1k"
#endif
#endif

static __device__ __forceinline__ unsigned short f2bf(float f){
  unsigned u = __builtin_bit_cast(unsigned, f);
  u += 0x7FFFu + ((u >> 16) & 1u);          // round-to-nearest-even
  return (unsigned short)(u >> 16);
}

static __device__ __forceinline__ f32x4 mfma32(bf16x8 a, bf16x8 b, f32x4 c){
  return __builtin_amdgcn_mfma_f32_16x16x32_bf16(a, b, c, 0, 0, 0);
}
static __device__ __forceinline__ f32x4 mfma16(bf16x4 a, bf16x4 b, f32x4 c){
  return __builtin_amdgcn_mfma_f32_16x16x16bf16_1k(a, b, c, 0, 0, 0);
}

static __device__ __forceinline__ bf16x8 wfrag(const unsigned short* __restrict__ W, int row, int k0){
  return *(const bf16x8*)(W + row*DIM + k0);
}

// ---- attn_mask dtype probe: 0 = int32 {0,1}, 1 = packed bytes, 2 = float32 ----
__global__ void detect_amask_kernel(const unsigned int* __restrict__ am, int* __restrict__ mode){
  __shared__ int sawFloat, sawByte;
  if (threadIdx.x == 0){ sawFloat = 0; sawByte = 0; }
  __syncthreads();
  const uint4 ld = ((const uint4*)am)[threadIdx.x];   // 256 threads * 16B = 4KB
  unsigned w[4] = {ld.x, ld.y, ld.z, ld.w};
  int f = 0, bm = 0;
  #pragma unroll
  for (int i = 0; i < 4; ++i){
    if (w[i] == 0x3F800000u) f = 1;
    else if (w[i] & ~1u)     bm = 1;
  }
  if (f)  atomicOr(&sawFloat, 1);
  if (bm) atomicOr(&sawByte, 1);
  __syncthreads();
  if (threadIdx.x == 0) *mode = sawFloat ? 2 : (sawByte ? 1 : 0);
}

// bias_t[h][n][m] = rpb_table[rel_idx[n][m]*HEADS + h]  (float4-loadable over m)
__global__ void bias_pre_kernel(const float* __restrict__ rpb, const int* __restrict__ rel_idx,
                                float* __restrict__ bias_t){
  const int e = blockIdx.x*256 + threadIdx.x;
  if (e >= HEADS*NTOK*NTOK) return;
  const int n = (e >> 6) & 63, m = e & 63;
  bias_t[e] = rpb[rel_idx[n*NTOK + m]*HEADS + (e >> 12)];
}

// convert the 4 weight matrices fp32 -> bf16 once (Wq,Wk,Wv,Wp contiguous in ws)
__global__ void wconv_kernel(const float* __restrict__ Wq, const float* __restrict__ Wk,
                             const float* __restrict__ Wv, const float* __restrict__ Wp,
                             unsigned short* __restrict__ wbf){
  const int e4 = blockIdx.x*256 + threadIdx.x;       // 4*36864/4 = 36864 float4s
  if (e4 >= 4*WMAT/4) return;
  const int mat = e4 / (WMAT/4);
  const int off = e4 - mat*(WMAT/4);
  const float* src = (mat==0)?Wq:(mat==1)?Wk:(mat==2)?Wv:Wp;
  const float4 f = ((const float4*)src)[off];
  unsigned short* dst = wbf + mat*WMAT + off*4;
  dst[0]=f2bf(f.x); dst[1]=f2bf(f.y); dst[2]=f2bf(f.z); dst[3]=f2bf(f.w);
}

// ============================ K1: projections ============================
// blockIdx = mat*2048 + w.  Stage x window in LDS (coalesced), multiply by
// L2-hot bf16 weights.  Outputs (bf16):
//   mat 0: Q' = (x@Wq^T+bq)*scale -> out rows bytes [0,384), layout [n][c]
//   mat 1: K' =  x@Wk^T+bk        -> out rows bytes [384,768), layout [m][c]
//   mat 2: V'^T[c][m]             -> ws Vt, row pitch 64 (per global c)
// Orientations chosen so stores are uint2 and K2 fragment loads are
// contiguous 8B. Fragment facts (m89-verified):
//   mfma32: A[row=l15][k=8g+i], B[k=8g+i][col=l15], C: col=l15, row=4g+r
__global__ __launch_bounds__(256, 4) void proj_kernel(
  const float* __restrict__ q, const float* __restrict__ kin, const float* __restrict__ vin,
  const unsigned short* __restrict__ wbf,
  const float* __restrict__ bq, const float* __restrict__ bk, const float* __restrict__ bv,
  char* __restrict__ outc, unsigned short* __restrict__ Vt)
{
  __shared__ unsigned short xs[NTOK * XPITCH];   // 25.6 KB

  const int bid = blockIdx.x;
  const int mat = bid >> 11;            // 0=q,1=k,2=v
  const int w   = bid & (NBLK-1);
  const int t   = threadIdx.x;
  const int wv  = t >> 6;
  const int lane= t & 63;
  const int l15 = lane & 15;
  const int g   = lane >> 4;
  const size_t base = (size_t)w * (NTOK * DIM);
  const float scale = 0.17677669529663687f;   // 1/sqrt(32)
  const f32x4 fz = {0.f, 0.f, 0.f, 0.f};

  const float* src = (mat==0) ? (q + base) : (mat==1) ? (kin + base) : (vin + base);

  // stage 64x192 fp32 -> bf16 LDS (3072 float4, 12 per thread, coalesced)
  #pragma unroll
  for (int j = 0; j < 12; ++j){
    const int i4  = t + j*256;
    const float4 f = ((const float4*)src)[i4];
    const int row = i4 / 48;
    const int col = (i4 - row*48) * 4;
    uint2 u;
    u.x = (unsigned)f2bf(f.x) | ((unsigned)f2bf(f.y) << 16);
    u.y = (unsigned)f2bf(f.z) | ((unsigned)f2bf(f.w) << 16);
    *(uint2*)(xs + row*XPITCH + col) = u;
  }
  __syncthreads();

  const int ct0 = wv*3;                 // each wave: 3 c-tiles (48 c), all 4 n/m tiles

  if (mat < 2){
    // transposed orientation: C[c][n], A=W rows c, B=x cols n
    const unsigned short* W = wbf + mat*WMAT;
    const float* bias = mat ? bk : bq;
    const float sc = mat ? 1.0f : scale;
    f32x4 acc[3][4];
    #pragma unroll
    for (int c=0;c<3;++c){
      #pragma unroll
      for (int nt=0;nt<4;++nt) acc[c][nt] = fz;
    }
    #pragma unroll
    for (int kt = 0; kt < 6; ++kt){
      const int k0 = kt*32 + g*8;
      bf16x8 wf[3];
      #pragma unroll
      for (int c=0;c<3;++c) wf[c] = wfrag(W, (ct0+c)*16 + l15, k0);
      #pragma unroll
      for (int nt = 0; nt < 4; ++nt){
        const bf16x8 xf = *(const bf16x8*)(xs + (nt*16 + l15)*XPITCH + k0);
        #pragma unroll
        for (int c=0;c<3;++c) acc[c][nt] = mfma32(wf[c], xf, acc[c][nt]);
      }
    }
    // store: C col=n(l15), row=c(4g+r): uint2 of 4 consecutive c per lane
    #pragma unroll
    for (int c=0;c<3;++c){
      const int ct = ct0 + c;
      const float4 bb = *(const float4*)(bias + ct*16 + g*4);
      #pragma unroll
      for (int nt = 0; nt < 4; ++nt){
        const int n = nt*16 + l15;
        uint2 u;
        u.x = (unsigned)f2bf((acc[c][nt][0]+bb.x)*sc) | ((unsigned)f2bf((acc[c][nt][1]+bb.y)*sc) << 16);
        u.y = (unsigned)f2bf((acc[c][nt][2]+bb.z)*sc) | ((unsigned)f2bf((acc[c][nt][3]+bb.w)*sc) << 16);
        *(uint2*)(outc + (base + (size_t)n*DIM)*4/1 /*row*768B*/ * 0 + (size_t)(w*NTOK + n)*768 + mat*384 + (ct*16 + g*4)*2) = u;
      }
    }
  } else {
    // normal orientation: C[m][c], A=x rows m, B=W cols c
    const unsigned short* W = wbf + 2*WMAT;
    f32x4 acc[4][3];
    #pragma unroll
    for (int mt=0;mt<4;++mt){
      #pragma unroll
      for (int c=0;c<3;++c) acc[mt][c] = fz;
    }
    #pragma unroll
    for (int kt = 0; kt < 6; ++kt){
      const int k0 = kt*32 + g*8;
      bf16x8 wf[3];
      #pragma unroll
      for (int c=0;c<3;++c) wf[c] = wfrag(W, (ct0+c)*16 + l15, k0);
      #pragma unroll
      for (int mt = 0; mt < 4; ++mt){
        const bf16x8 xf = *(const bf16x8*)(xs + (mt*16 + l15)*XPITCH + k0);
        #pragma unroll
        for (int c=0;c<3;++c) acc[mt][c] = mfma32(xf, wf[c], acc[mt][c]);
      }
    }
    // store: C col=c(l15), row=m(4g+r): uint2 of 4 consecutive m -> Vt[c][m]
    #pragma unroll
    for (int c=0;c<3;++c){
      const int cc = (ct0 + c)*16 + l15;          // global c = h*32+d
      const float bvv = bv[cc];
      #pragma unroll
      for (int mt = 0; mt < 4; ++mt){
        uint2 u;
        u.x = (unsigned)f2bf(acc[mt][c][0]+bvv) | ((unsigned)f2bf(acc[mt][c][1]+bvv) << 16);
        u.y = (unsigned)f2bf(acc[mt][c][2]+bvv) | ((unsigned)f2bf(acc[mt][c][3]+bvv) << 16);
        *(uint2*)(Vt + ((size_t)w*DIM + cc)*NTOK + mt*16 + g*4) = u;
      }
    }
  }
}

// ============================ K2: attention ============================
// 2048 blocks x 384 thr; wave = head; 0 LDS, 0 barriers. All operand loads
// are contiguous 8B fragments from the layouts K1 produced.
//   mfma16: A[row=l15][k=4g+r], B[k=4g+r][col=l15], C: col=l15, row=4g+r
// xout (bf16) overwrites this wave's OWN Q' chunk (bytes [h*64,h*64+64) of
// rows' front half) — value-dependent on its reads, disjoint across waves.
__global__ __launch_bounds__(384, 2) void attn_kernel(
  const float* __restrict__ mask, const void* __restrict__ amask,
  const float* __restrict__ bias_t, const int* __restrict__ mflag,
  char* __restrict__ outc, const unsigned short* __restrict__ Vt)
{
  const int b    = blockIdx.x;
  const int t    = threadIdx.x;
  const int h    = t >> 6;
  const int lane = t & 63;
  const int l15  = lane & 15;
  const int g    = lane >> 4;
  const f32x4 fz = {0.f, 0.f, 0.f, 0.f};

  bf16x4 Qf[4][2], Kf[4][2], Vf[2][4];
  // Q' frag: element [c=dt*16+4g+r][n=nt*16+l15] -> 8B at row n, col c
  #pragma unroll
  for (int nt = 0; nt < 4; ++nt){
    const size_t rowb = (size_t)(b*NTOK + nt*16 + l15)*768 + h*64;
    #pragma unroll
    for (int dt = 0; dt < 2; ++dt){
      Qf[nt][dt] = *(const bf16x4*)(outc + rowb + (dt*16 + g*4)*2);
      Kf[nt][dt] = *(const bf16x4*)(outc + rowb + 384 + (dt*16 + g*4)*2);
    }
  }
  // V frag: element [d=dt*16+l15][m=mt*16+4g+r] -> 8B in Vt row (h*32+d)
  #pragma unroll
  for (int dt = 0; dt < 2; ++dt){
    const size_t rowv = ((size_t)b*DIM + h*HD + dt*16 + l15)*NTOK;
    #pragma unroll
    for (int mt = 0; mt < 4; ++mt){
      Vf[dt][mt] = *(const bf16x4*)(Vt + rowv + mt*16 + g*4);
    }
  }

  // ---------- S^T = Kh * Qh^T : C[col=n=l15+16nt][row=m=4g+r+16mt] ----------
  f32x4 s[4][4];
  #pragma unroll
  for (int mt = 0; mt < 4; ++mt){
    #pragma unroll
    for (int nt = 0; nt < 4; ++nt){
      f32x4 a = mfma16(Kf[mt][0], Qf[nt][0], fz);
      s[mt][nt] = mfma16(Kf[mt][1], Qf[nt][1], a);
    }
  }

  // ---------- mask + attn_mask + bias folded per-lane from global ----------
  {
    const int mode = mflag[0];
    const float* mrow = mask + (size_t)(b & (NWIN-1)) * (NTOK*NTOK);
    const float* brow = bias_t + h * (NTOK*NTOK);
    #pragma unroll
    for (int nt = 0; nt < 4; ++nt){
      const int n = nt*16 + l15;
      #pragma unroll
      for (int mt = 0; mt < 4; ++mt){
        const int off = n*NTOK + mt*16 + g*4;
        const float4 mk = *(const float4*)(mrow + off);
        const float4 bi = *(const float4*)(brow + off);
        float am[4];
        if (mode == 0){
          const int4 a4 = *(const int4*)((const int*)amask + (size_t)b*(NTOK*NTOK) + off);
          am[0] = a4.x ? -1e9f : 0.f; am[1] = a4.y ? -1e9f : 0.f;
          am[2] = a4.z ? -1e9f : 0.f; am[3] = a4.w ? -1e9f : 0.f;
        } else if (mode == 1){
          const unsigned a4 = *(const unsigned*)((const unsigned char*)amask + (size_t)b*(NTOK*NTOK) + off);
          am[0] = (a4 & 0x000000FFu) ? -1e9f : 0.f; am[1] = (a4 & 0x0000FF00u) ? -1e9f : 0.f;
          am[2] = (a4 & 0x00FF0000u) ? -1e9f : 0.f; am[3] = (a4 & 0xFF000000u) ? -1e9f : 0.f;
        } else {
          const float4 a4 = *(const float4*)((const float*)amask + (size_t)b*(NTOK*NTOK) + off);
          am[0] = (a4.x != 0.f) ? -1e9f : 0.f; am[1] = (a4.y != 0.f) ? -1e9f : 0.f;
          am[2] = (a4.z != 0.f) ? -1e9f : 0.f; am[3] = (a4.w != 0.f) ? -1e9f : 0.f;
        }
        s[mt][nt][0] += mk.x + bi.x + am[0];
        s[mt][nt][1] += mk.y + bi.y + am[1];
        s[mt][nt][2] += mk.z + bi.z + am[2];
        s[mt][nt][3] += mk.w + bi.w + am[3];
      }
    }
  }

  // ---------- softmax over m (in-lane 16 + shfl_xor 16,32) ----------
  bf16x4 Pf[4][4];
  #pragma unroll
  for (int nt = 0; nt < 4; ++nt){
    float mx = -3.0e38f;
    #pragma unroll
    for (int mt = 0; mt < 4; ++mt){
      #pragma unroll
      for (int r = 0; r < 4; ++r) mx = fmaxf(mx, s[mt][nt][r]);
    }
    mx = fmaxf(mx, __shfl_xor(mx, 16, 64));
    mx = fmaxf(mx, __shfl_xor(mx, 32, 64));
    float sum = 0.f;
    #pragma unroll
    for (int mt = 0; mt < 4; ++mt){
      #pragma unroll
      for (int r = 0; r < 4; ++r){
        const float e = __expf(s[mt][nt][r] - mx);
        s[mt][nt][r] = e;
        sum += e;
      }
    }
    sum += __shfl_xor(sum, 16, 64);
    sum += __shfl_xor(sum, 32, 64);
    const float inv = 1.0f / sum;
    #pragma unroll
    for (int ms = 0; ms < 4; ++ms){
      bf16x4 f;
      f[0]=(short)f2bf(s[ms][nt][0]*inv); f[1]=(short)f2bf(s[ms][nt][1]*inv);
      f[2]=(short)f2bf(s[ms][nt][2]*inv); f[3]=(short)f2bf(s[ms][nt][3]*inv);
      Pf[nt][ms] = f;   // B-frag: P^T[m=4g+r+16ms][n=l15+16nt]
    }
  }

  // ---------- out^T = Vh^T * P^T : C[col=n][row=d=4g+r+16dt] ----------
  f32x4 o[2][4];
  #pragma unroll
  for (int a0=0;a0<2;++a0){
    #pragma unroll
    for (int a1=0;a1<4;++a1) o[a0][a1] = fz;
  }
  #pragma unroll
  for (int ms = 0; ms < 4; ++ms){
    #pragma unroll
    for (int dt = 0; dt < 2; ++dt){
      #pragma unroll
      for (int nt = 0; nt < 4; ++nt){
        o[dt][nt] = mfma16(Vf[dt][ms], Pf[nt][ms], o[dt][nt]);
      }
    }
  }

  // ---------- xout bf16 over own Q' chunk: [n][c] layout, uint2 stores ----------
  #pragma unroll
  for (int dt = 0; dt < 2; ++dt){
    #pragma unroll
    for (int nt = 0; nt < 4; ++nt){
      const int n = nt*16 + l15;
      uint2 u;
      u.x = (unsigned)f2bf(o[dt][nt][0]) | ((unsigned)f2bf(o[dt][nt][1]) << 16);
      u.y = (unsigned)f2bf(o[dt][nt][2]) | ((unsigned)f2bf(o[dt][nt][3]) << 16);
      *(uint2*)(outc + (size_t)(b*NTOK + n)*768 + h*64 + (dt*16 + g*4)*2) = u;
    }
  }
}

// ============================ K3: output projection ============================
// out[n][c'] = xout[n][:] @ Wp[c'][:]^T + bp ; xout bf16 in row fronts [0,384),
// fp32 result overwrites the full row. Stores depend (via MFMA chain) on all
// the wave's loads; each wave owns its 16 rows exclusively.
__global__ __launch_bounds__(256, 4) void oproj_kernel(
  float* __restrict__ outf, const unsigned short* __restrict__ wbf,
  const float* __restrict__ bp)
{
  const int t    = threadIdx.x;
  const int wv   = t >> 6;
  const int lane = t & 63;
  const int l15  = lane & 15;
  const int g    = lane >> 4;
  const int n0   = (blockIdx.x*4 + wv) * 16;     // 16 tokens per wave
  const unsigned short* Wp = wbf + 3*WMAT;
  const f32x4 fz = {0.f, 0.f, 0.f, 0.f};

  f32x4 acc[12];
  #pragma unroll
  for (int ct = 0; ct < 12; ++ct) acc[ct] = fz;

  #pragma unroll
  for (int kt = 0; kt < 6; ++kt){
    const int k0 = kt*32 + g*8;
    const bf16x8 a = *(const bf16x8*)((const char*)outf + (size_t)(n0 + l15)*768 + k0*2);
    #pragma unroll
    for (int ct = 0; ct < 12; ++ct){
      const bf16x8 w = wfrag(Wp, ct*16 + l15, k0);
      acc[ct] = mfma32(a, w, acc[ct]);
    }
  }
  #pragma unroll
  for (int ct = 0; ct < 12; ++ct){
    const float badd = bp[ct*16 + l15];
    #pragma unroll
    for (int r = 0; r < 4; ++r){
      outf[(size_t)(n0 + g*4 + r)*DIM + ct*16 + l15] = acc[ct][r] + badd;
    }
  }
}

extern "C" void kernel_launch(void* const* d_in, const int* in_sizes, int n_in,
                              void* d_out, int out_size, void* d_ws, size_t ws_size,
                              hipStream_t stream){
  const float* q     = (const float*)d_in[0];
  const float* k     = (const float*)d_in[1];
  const float* v     = (const float*)d_in[2];
  const float* mask  = (const float*)d_in[3];
  const void*  amask = d_in[4];               // dtype resolved by device probe
  const float* Wq    = (const float*)d_in[5];
  const float* bq    = (const float*)d_in[6];
  const float* Wk    = (const float*)d_in[7];
  const float* bk    = (const float*)d_in[8];
  const float* Wv    = (const float*)d_in[9];
  const float* bv    = (const float*)d_in[10];
  const float* Wp    = (const float*)d_in[11];
  const float* bp    = (const float*)d_in[12];
  const float* rpb   = (const float*)d_in[13];
  const int*   ridx  = (const int*)d_in[14];
  float* out = (float*)d_out;

  // ws layout: [0,98304) bias_t | [98304,98308) mflag | [98560,393472) wbf
  //            | [524288, +50.3MB) Vt
  float*          bias_t = (float*)d_ws;
  int*            mflag  = (int*)((char*)d_ws + 98304);
  unsigned short* wbf    = (unsigned short*)((char*)d_ws + 98560);
  unsigned short* Vt     = (unsigned short*)((char*)d_ws + 524288);

  detect_amask_kernel<<<1, 256, 0, stream>>>((const unsigned int*)amask, mflag);
  bias_pre_kernel<<<96, 256, 0, stream>>>(rpb, ridx, bias_t);
  wconv_kernel<<<144, 256, 0, stream>>>(Wq, Wk, Wv, Wp, wbf);
  proj_kernel<<<3*NBLK, 256, 0, stream>>>(q, k, v, wbf, bq, bk, bv, (char*)out, Vt);
  attn_kernel<<<NBLK, 384, 0, stream>>>(mask, amask, bias_t, mflag, (char*)out, Vt);
  oproj_kernel<<<NBLK, 256, 0, stream>>>(out, wbf, bp);
}